// Round 4
// baseline (276.770 us; speedup 1.0000x reference)
//
#include <hip/hip_runtime.h>
#include <stdint.h>

#define DIM   256
#define BATCH 8192
#define MCELL 4096

typedef unsigned long long u64;
typedef unsigned short u16;
typedef __attribute__((ext_vector_type(8))) short bf16x8;   // 8 bf16 = 4 VGPRs
typedef __attribute__((ext_vector_type(4))) float f32x4;

// ---------------- helpers ----------------
__device__ __forceinline__ u64 packMin(float v, unsigned idx) {
    unsigned u = __float_as_uint(v);
    u = (u & 0x80000000u) ? ~u : (u | 0x80000000u);   // order-preserving f32->u32
    return ((u64)u << 32) | (u64)idx;
}
__device__ __forceinline__ u16 f2bf(float f) {        // RN-even f32->bf16 (bits)
    unsigned u = __float_as_uint(f);
    u += 0x7fffu + ((u >> 16) & 1u);
    return (u16)(u >> 16);
}
__device__ __forceinline__ void gll16(const void* g, const char* l) {
    __builtin_amdgcn_global_load_lds(
        (const __attribute__((address_space(1))) unsigned int*)g,
        (__attribute__((address_space(3))) unsigned int*)l, 16, 0, 0);
}

// ---------------- w2 (+ scal on extra block) ----------------
__global__ void k_w2(const float* __restrict__ W, float* __restrict__ w2,
                     const int* __restrict__ epoch_p, float* __restrict__ scal) {
    if (blockIdx.x == 1024) {   // scal part: E[64] table + alpha
        int t = threadIdx.x;
        int raw = epoch_p[0];
        float ep = (raw >= 0 && raw < 100000) ? (float)raw : __int_as_float(raw);
        float radius = 32.0f - ep * (31.0f / 99.0f);
        float alpha  = 0.1f * (1.0f - ep / 100.0f);
        float rs = radius * 0.5f;
        float denom = 2.0f * rs * rs;
        if (t < 64)       scal[t]  = expf(-((float)(t * t)) / denom);
        else if (t == 64) scal[64] = alpha;
        return;
    }
    int lane = threadIdx.x & 63;
    int row  = blockIdx.x * 4 + (threadIdx.x >> 6);
    float4 v = *(const float4*)(W + (size_t)row * DIM + lane * 4);
    float s = v.x * v.x + v.y * v.y + v.z * v.z + v.w * v.w;
    #pragma unroll
    for (int off = 32; off; off >>= 1) s += __shfl_down(s, off);
    if (lane == 0) w2[row] = s;
}

// ---------------- hi/lo bf16 split (X and W in one launch) ----------------
__global__ void k_split(const float* __restrict__ X, const float* __restrict__ W,
                        u16* __restrict__ Xh, u16* __restrict__ Xl,
                        u16* __restrict__ Wh, u16* __restrict__ Wl) {
    const int blk = blockIdx.x;
    const float* src; u16 *hi, *lo; int i;
    if (blk < 2048) { i = blk * 256 + threadIdx.x; src = X; hi = Xh; lo = Xl; }
    else { i = (blk - 2048) * 256 + threadIdx.x; src = W; hi = Wh; lo = Wl; }
    float4 v = ((const float4*)src)[i];
    float f[4] = {v.x, v.y, v.z, v.w};
    u16 h[4], l[4];
    #pragma unroll
    for (int q = 0; q < 4; ++q) {
        h[q] = f2bf(f[q]);
        float hf = __uint_as_float((unsigned)h[q] << 16);
        l[q] = f2bf(f[q] - hf);
    }
    ushort4 hv = {h[0], h[1], h[2], h[3]}, lv = {l[0], l[1], l[2], l[3]};
    ((ushort4*)hi)[i] = hv;
    ((ushort4*)lo)[i] = lv;
}

// ---------------- MFMA split-bf16 GEMM (LDS dbuf) + per-row global top-2 ----
// grid 2048 = 64 b-tiles(128) x 32 m-tiles(128); 4 waves = 2b x 2m, wave 64x64.
// LDS: 2 x {Ah,Al,Bh,Bl} 128x32 bf16 tiles = 64 KB, XOR-swizzled slots.
__global__ __launch_bounds__(256, 2)
void k_gemm_argmin(const u16* __restrict__ Xh, const u16* __restrict__ Xl,
                   const u16* __restrict__ Wh, const u16* __restrict__ Wl,
                   const float* __restrict__ w2,
                   u64* __restrict__ P1, u64* __restrict__ P2) {
    __shared__ char smem[65536];
    const int wg = blockIdx.x;
    const int swz = (wg & 7) * 256 + (wg >> 3);   // XCD-chunked, bijective (2048%8==0)
    const int bt = swz >> 5;                      // 0..63
    const int mt = swz & 31;                      // 0..31
    const int tid = threadIdx.x;
    const int wid = tid >> 6;
    const int lane = tid & 63;
    const int wr = wid >> 1, wc = wid & 1;
    const int b0 = bt * 128, m0 = mt * 128;
    const int b0w = b0 + wr * 64, m0w = m0 + wc * 64;

    // ---- staging addresses (constant per lane; + c*32 elements per chunk) ----
    const int srow0 = wid * 32 + (lane >> 2);     // issue 0 row; issue 1 = +16
    const int sslot = lane & 3;
    const int r0 = srow0, r1 = srow0 + 16;
    const int sg0 = sslot ^ ((r0 >> 1) & 3);      // pre-swizzled global slot
    const int sg1 = sslot ^ ((r1 >> 1) & 3);
    const size_t gA0 = (size_t)(b0 + r0) * DIM + sg0 * 8;
    const size_t gA1 = (size_t)(b0 + r1) * DIM + sg1 * 8;
    const size_t gB0 = (size_t)(m0 + r0) * DIM + sg0 * 8;
    const size_t gB1 = (size_t)(m0 + r1) * DIM + sg1 * 8;
    const int ldso = wid * 2048;                  // wave-uniform LDS base offset

    // ---- fragment read offsets (bytes within one 8KB tile), swizzled ----
    const int rl = lane & 15, g = lane >> 4;
    const int slot = g ^ ((rl >> 1) & 3);
    const int aoff = (wr * 64 + rl) * 64 + slot * 16;   // + i*1024
    const int boff = (wc * 64 + rl) * 64 + slot * 16;   // + j*1024

    // preload w2 (before any STAGE so vmcnt FIFO counting stays exact)
    float w2v[4];
    #pragma unroll
    for (int j = 0; j < 4; ++j) {
        w2v[j] = w2[m0w + j * 16 + rl];
        asm volatile("" :: "v"(w2v[j]));   // pin: materialize now
    }

    f32x4 acc[4][4];
    #pragma unroll
    for (int i = 0; i < 4; ++i)
        #pragma unroll
        for (int j = 0; j < 4; ++j) acc[i][j] = (f32x4){0.f, 0.f, 0.f, 0.f};

    #define STAGE(buf, c) do {                                                \
        char* base_ = smem + (buf) * 32768;                                   \
        const int co_ = (c) * 32;                                             \
        gll16(Xh + gA0 + co_, base_ + ldso);                                  \
        gll16(Xh + gA1 + co_, base_ + ldso + 1024);                           \
        gll16(Xl + gA0 + co_, base_ + 8192 + ldso);                           \
        gll16(Xl + gA1 + co_, base_ + 8192 + ldso + 1024);                    \
        gll16(Wh + gB0 + co_, base_ + 16384 + ldso);                          \
        gll16(Wh + gB1 + co_, base_ + 16384 + ldso + 1024);                   \
        gll16(Wl + gB0 + co_, base_ + 24576 + ldso);                          \
        gll16(Wl + gB1 + co_, base_ + 24576 + ldso + 1024);                   \
    } while (0)

    STAGE(0, 0);
    #pragma unroll
    for (int c = 0; c < 8; ++c) {
        const int cur = c & 1;
        if (c < 7) {
            STAGE(cur ^ 1, c + 1);
            asm volatile("s_waitcnt vmcnt(8)" ::: "memory");   // cur's 8 done, next 8 in flight
        } else {
            asm volatile("s_waitcnt vmcnt(0)" ::: "memory");
        }
        __builtin_amdgcn_sched_barrier(0);
        __builtin_amdgcn_s_barrier();

        const char* bufc = smem + cur * 32768;
        bf16x8 ah[4], al[4];
        #pragma unroll
        for (int i = 0; i < 4; ++i) {
            ah[i] = *(const bf16x8*)(bufc + aoff + i * 1024);
            al[i] = *(const bf16x8*)(bufc + 8192 + aoff + i * 1024);
        }
        #pragma unroll
        for (int j = 0; j < 4; ++j) {
            const bf16x8 bh = *(const bf16x8*)(bufc + 16384 + boff + j * 1024);
            const bf16x8 bl = *(const bf16x8*)(bufc + 24576 + boff + j * 1024);
            #pragma unroll
            for (int i = 0; i < 4; ++i) {
                acc[i][j] = __builtin_amdgcn_mfma_f32_16x16x32_bf16(ah[i], bh, acc[i][j], 0, 0, 0);
                acc[i][j] = __builtin_amdgcn_mfma_f32_16x16x32_bf16(ah[i], bl, acc[i][j], 0, 0, 0);
                acc[i][j] = __builtin_amdgcn_mfma_f32_16x16x32_bf16(al[i], bh, acc[i][j], 0, 0, 0);
            }
        }
        __builtin_amdgcn_s_barrier();
    }
    #undef STAGE

    // epilogue: d~ = w2[m] - 2*dot; per-row top-2 over the wave's 64 m
    #pragma unroll
    for (int i = 0; i < 4; ++i) {
        #pragma unroll
        for (int q = 0; q < 4; ++q) {
            u64 best = ~0ull, sec = ~0ull;
            #pragma unroll
            for (int j = 0; j < 4; ++j) {
                float d = w2v[j] - 2.0f * acc[i][j][q];
                u64 p = packMin(d, (unsigned)(m0w + j * 16 + rl));
                if (p < best) { sec = best; best = p; }
                else if (p < sec) { sec = p; }
            }
            #pragma unroll
            for (int off = 1; off <= 8; off <<= 1) {   // reduce 16 lanes (same g)
                u64 ob = __shfl_xor(best, off);
                u64 os = __shfl_xor(sec, off);
                u64 nb  = ob < best ? ob : best;
                u64 hi2 = ob < best ? best : ob;
                u64 ns  = os < sec ? os : sec;
                ns = hi2 < ns ? hi2 : ns;
                best = nb; sec = ns;
            }
            if (rl == 0) {
                const int row = b0w + i * 16 + g * 4 + q;
                u64 old = atomicMin(&P1[row], best);
                u64 c2 = (best < old) ? (old < sec ? old : sec) : best;
                atomicMin(&P2[row], c2);   // P2 ends as exact global 2nd-best
            }
        }
    }
}

// ---------------- exact f32 recheck of the two candidates ----------------
__global__ void k_recheck(const u64* __restrict__ P1, const u64* __restrict__ P2,
                          const float* __restrict__ X, const float* __restrict__ W,
                          const float* __restrict__ w2, int* __restrict__ bmu,
                          float* __restrict__ out_locs) {
    const int row  = blockIdx.x * 4 + (threadIdx.x >> 6);
    const int lane = threadIdx.x & 63;
    const int m1 = (int)(P1[row] & 0xFFFFFFFFull);
    const int m2 = (int)(P2[row] & 0xFFFFFFFFull);
    const float4 xv = *(const float4*)(X + (size_t)row * DIM + lane * 4);
    const float4 a  = *(const float4*)(W + (size_t)m1 * DIM + lane * 4);
    const float4 b  = *(const float4*)(W + (size_t)m2 * DIM + lane * 4);
    float p1 = xv.x * a.x + xv.y * a.y + xv.z * a.z + xv.w * a.w;
    float p2 = xv.x * b.x + xv.y * b.y + xv.z * b.z + xv.w * b.w;
    #pragma unroll
    for (int off = 32; off; off >>= 1) {
        p1 += __shfl_xor(p1, off);
        p2 += __shfl_xor(p2, off);
    }
    if (lane == 0) {
        float d1 = w2[m1] - 2.0f * p1;
        float d2 = w2[m2] - 2.0f * p2;
        int mw = (d2 < d1 || (d2 == d1 && m2 < m1)) ? m2 : m1;
        bmu[row] = mw;
        out_locs[row * 2 + 0] = (float)(mw >> 6);
        out_locs[row * 2 + 1] = (float)(mw & 63);
    }
}

// ---------------- scatter: per-cell accumulation ----------------
__global__ void k_scatter(const int* __restrict__ bmu, const float* __restrict__ X,
                          float* __restrict__ A, float* __restrict__ cnt) {
    const int b = blockIdx.x;
    const int m = bmu[b];
    const int d = threadIdx.x;
    atomicAdd(&A[(size_t)m * DIM + d], X[(size_t)b * DIM + d]);
    if (d == 0) atomicAdd(&cnt[m], 1.0f);
}

// ---------------- conv pass 1 (over gj) + cnt1 on extra blocks ----------------
__global__ void k_conv1(const float* __restrict__ A, const float* __restrict__ E,
                        float* __restrict__ T1, const float* __restrict__ cnt,
                        float* __restrict__ c1) {
    if (blockIdx.x >= 4096) {   // cnt1: c1[gi][mj] = sum_gj E|mj-gj| cnt[gi][gj]
        int t = (blockIdx.x - 4096) * 256 + threadIdx.x;
        int gi = t >> 6, mj = t & 63;
        float acc = 0.0f;
        #pragma unroll
        for (int gj = 0; gj < 64; ++gj) {
            int dd = mj - gj; dd = dd < 0 ? -dd : dd;
            acc += E[dd] * cnt[gi * 64 + gj];
        }
        c1[gi * 64 + mj] = acc;
        return;
    }
    __shared__ float Es[64];
    const int d = threadIdx.x;
    if (d < 64) Es[d] = E[d];
    __syncthreads();
    const int gi = blockIdx.x >> 6, mj = blockIdx.x & 63;
    const float* base = A + (size_t)gi * 64 * DIM + d;
    float acc = 0.0f;
    #pragma unroll
    for (int gj = 0; gj < 64; ++gj) {
        int dd = mj - gj; dd = dd < 0 ? -dd : dd;
        acc += Es[dd] * base[(size_t)gj * DIM];
    }
    T1[(size_t)blockIdx.x * DIM + d] = acc;   // [gi][mj][d]
}

// ---------------- conv pass 2 (over gi) + inline den + divide + write --------
__global__ void k_conv2(const float* __restrict__ T1, const float* __restrict__ scal,
                        const float* __restrict__ c1, float* __restrict__ outw) {
    __shared__ float Es[64];
    __shared__ float salpha;
    const int d = threadIdx.x;
    if (d < 64) Es[d] = scal[d];
    if (d == 64) salpha = scal[64];
    __syncthreads();
    const int mi = blockIdx.x >> 6, mj = blockIdx.x & 63;
    float acc = 0.0f, den = 0.0f;
    #pragma unroll
    for (int gi = 0; gi < 64; ++gi) {
        int dd = mi - gi; dd = dd < 0 ? -dd : dd;
        acc += Es[dd] * T1[((size_t)gi * 64 + mj) * DIM + d];
        den += Es[dd] * c1[gi * 64 + mj];      // broadcast load, L2-resident
    }
    const float a = salpha;
    const float v = (a * acc) / (a * den + 1e-12f);
    outw[((size_t)mi * 64 + mj) * DIM + d] = v;
}

// ---------------- launcher ----------------
extern "C" void kernel_launch(void* const* d_in, const int* in_sizes, int n_in,
                              void* d_out, int out_size, void* d_ws, size_t ws_size,
                              hipStream_t stream) {
    const float* X = (const float*)d_in[0];
    const float* W = (const float*)d_in[1];
    const int*   ep = (const int*)d_in[2];
    float* out = (float*)d_out;

    char* ws = (char*)d_ws;
    u64*   P1   = (u64*)(ws + 0);                  // 64 KB
    u64*   P2   = (u64*)(ws + 65536);              // 64 KB
    int*   bmu  = (int*)(ws + 131072);             // 32 KB
    float* w2   = (float*)(ws + 163840);           // 16 KB
    float* scal = (float*)(ws + 180224);           // 65 floats
    float* cnt  = (float*)(ws + 184320);           // 16 KB
    float* c1   = (float*)(ws + 200704);           // 16 KB
    u16*   Xh   = (u16*)(ws + 262144);             // 4 MB
    u16*   Xl   = (u16*)(ws + 262144 + (4u<<20));  // 4 MB
    u16*   Wh   = (u16*)(ws + 262144 + (8u<<20));  // 2 MB
    u16*   Wl   = (u16*)(ws + 262144 + (10u<<20)); // 2 MB
    float* A    = (float*)(ws + 262144 + (8u<<20));   // 4 MB, aliases Wh/Wl (dead after gemm)
    float* T1   = (float*)(ws + 262144);              // 4 MB, aliases Xh (dead after gemm)

    hipMemsetAsync(ws, 0xFF, 131072, stream);      // P1,P2 = +inf packed

    k_w2<<<1025, 256, 0, stream>>>(W, w2, ep, scal);
    k_split<<<3072, 256, 0, stream>>>(X, W, Xh, Xl, Wh, Wl);
    k_gemm_argmin<<<2048, 256, 0, stream>>>(Xh, Xl, Wh, Wl, w2, P1, P2);
    hipMemsetAsync(A, 0, 4u << 20, stream);        // after gemm (aliases W splits)
    hipMemsetAsync(cnt, 0, 16384, stream);
    k_recheck<<<2048, 256, 0, stream>>>(P1, P2, X, W, w2, bmu, out);
    k_scatter<<<BATCH, 256, 0, stream>>>(bmu, X, A, cnt);
    k_conv1<<<4112, 256, 0, stream>>>(A, scal, T1, cnt, c1);
    k_conv2<<<4096, 256, 0, stream>>>(T1, scal, c1, out + 16384);
}

// Round 5
// 200.504 us; speedup vs baseline: 1.3804x; 1.3804x over previous
//
#include <hip/hip_runtime.h>
#include <stdint.h>

#define DIM   256
#define BATCH 8192
#define MCELL 4096

typedef unsigned long long u64;
typedef unsigned short u16;
typedef __attribute__((ext_vector_type(8))) short bf16x8;   // 8 bf16 = 4 VGPRs
typedef __attribute__((ext_vector_type(4))) float f32x4;

// ---------------- helpers ----------------
__device__ __forceinline__ u64 packMin(float v, unsigned idx) {
    unsigned u = __float_as_uint(v);
    u = (u & 0x80000000u) ? ~u : (u | 0x80000000u);   // order-preserving f32->u32
    return ((u64)u << 32) | (u64)idx;
}
__device__ __forceinline__ u16 f2bf(float f) {        // RN-even f32->bf16 (bits)
    unsigned u = __float_as_uint(f);
    u += 0x7fffu + ((u >> 16) & 1u);
    return (u16)(u >> 16);
}
__device__ __forceinline__ void gll16(const void* g, const char* l) {
    __builtin_amdgcn_global_load_lds(
        (const __attribute__((address_space(1))) unsigned int*)g,
        (__attribute__((address_space(3))) unsigned int*)l, 16, 0, 0);
}
__device__ __forceinline__ u64 umin64(u64 a, u64 b) { return a < b ? a : b; }
__device__ __forceinline__ u64 umax64(u64 a, u64 b) { return a < b ? b : a; }
// merge two sorted triples -> sorted top-3 of the union (in a1,a2,a3)
__device__ __forceinline__ void merge3(u64& a1, u64& a2, u64& a3,
                                       u64 o1, u64 o2, u64 o3) {
    u64 L1 = umin64(a1, o1), H1 = umax64(a1, o1);
    u64 L2 = umin64(a2, o2);
    u64 L3 = umin64(a3, o3);
    a1 = L1;
    a2 = umin64(H1, L2);
    a3 = umin64(umax64(H1, L2), L3);
}

// ---------------- prep: bf16 casts + w2 + scal, one launch ----------------
__global__ void k_prep(const float* __restrict__ X, const float* __restrict__ W,
                       u16* __restrict__ Xh, u16* __restrict__ Wh,
                       float* __restrict__ w2, const int* __restrict__ epoch_p,
                       float* __restrict__ scal) {
    const int blk = blockIdx.x;
    const int t = threadIdx.x;
    if (blk == 3072) {   // scal: E[64] table + alpha
        int raw = epoch_p[0];
        float ep = (raw >= 0 && raw < 100000) ? (float)raw : __int_as_float(raw);
        float radius = 32.0f - ep * (31.0f / 99.0f);
        float alpha  = 0.1f * (1.0f - ep / 100.0f);
        float rs = radius * 0.5f;
        float denom = 2.0f * rs * rs;
        if (t < 64)       scal[t]  = expf(-((float)(t * t)) / denom);
        else if (t == 64) scal[64] = alpha;
        return;
    }
    if (blk < 2048) {            // X cast
        const int fi = blk * 256 + t;
        float4 v = ((const float4*)X)[fi];
        ushort4 h = {f2bf(v.x), f2bf(v.y), f2bf(v.z), f2bf(v.w)};
        ((ushort4*)Xh)[fi] = h;
    } else {                     // W cast + w2
        const int fi = (blk - 2048) * 256 + t;
        float4 v = ((const float4*)W)[fi];
        ushort4 h = {f2bf(v.x), f2bf(v.y), f2bf(v.z), f2bf(v.w)};
        ((ushort4*)Wh)[fi] = h;
        float s = v.x * v.x + v.y * v.y + v.z * v.z + v.w * v.w;
        #pragma unroll
        for (int off = 32; off; off >>= 1) s += __shfl_down(s, off);
        if ((t & 63) == 0) w2[fi >> 6] = s;
    }
}

// ---------------- hi-only bf16 MFMA GEMM + exact per-(row,mtile) top-3 ------
// block 128b x 128m, 4 waves (2x2), wave 64x64; BK=32, 8 chunks, 3-buf 2-ahead.
// LDS: 3 x {A 8KB, B 8KB} = 48 KB. Writes sorted top-3 slots (no atomics).
__global__ __launch_bounds__(256, 3)
void k_gemm_argmin(const u16* __restrict__ Xh, const u16* __restrict__ Wh,
                   const float* __restrict__ w2, u64* __restrict__ slots) {
    __shared__ char smem[49152];
    const int wg = blockIdx.x;
    const int swz = (wg & 7) * 256 + (wg >> 3);   // XCD-chunked, bijective (2048%8==0)
    const int bt = swz >> 5;                      // 0..63
    const int mt = swz & 31;                      // 0..31
    const int tid = threadIdx.x;
    const int wid = tid >> 6;
    const int lane = tid & 63;
    const int wr = wid >> 1, wc = wid & 1;
    const int b0 = bt * 128, m0 = mt * 128;
    const int m0w = m0 + wc * 64;

    // staging addrs: per wave 2 issues per array; rows [wid*32,+16), [+16,+16)
    const int sr0 = wid * 32 + (lane >> 2);
    const int sr1 = sr0 + 16;
    const int ss  = lane & 3;
    const int sg0 = ss ^ ((sr0 >> 1) & 3);        // pre-swizzled global slot
    const int sg1 = ss ^ ((sr1 >> 1) & 3);
    const size_t gA0 = (size_t)(b0 + sr0) * DIM + sg0 * 8;
    const size_t gA1 = (size_t)(b0 + sr1) * DIM + sg1 * 8;
    const size_t gB0 = (size_t)(m0 + sr0) * DIM + sg0 * 8;
    const size_t gB1 = (size_t)(m0 + sr1) * DIM + sg1 * 8;
    const int ldsA = wid * 2048;                  // wave-uniform within 8KB region

    // fragment read offsets (swizzled, both-sides involution)
    const int rl = lane & 15, g = lane >> 4;
    const int slot = g ^ ((rl >> 1) & 3);
    const int aoff = (wr * 64 + rl) * 64 + slot * 16;   // + i*1024
    const int boff = (wc * 64 + rl) * 64 + slot * 16;   // + j*1024

    f32x4 acc[4][4];
    #pragma unroll
    for (int i = 0; i < 4; ++i)
        #pragma unroll
        for (int j = 0; j < 4; ++j) acc[i][j] = (f32x4){0.f, 0.f, 0.f, 0.f};

    #define STAGE(buf, c) do {                                                \
        char* base_ = smem + (buf) * 16384;                                   \
        const int co_ = (c) * 32;                                             \
        gll16(Xh + gA0 + co_, base_ + ldsA);                                  \
        gll16(Xh + gA1 + co_, base_ + ldsA + 1024);                           \
        gll16(Wh + gB0 + co_, base_ + 8192 + ldsA);                           \
        gll16(Wh + gB1 + co_, base_ + 8192 + ldsA + 1024);                    \
    } while (0)

    STAGE(0, 0);
    STAGE(1, 1);
    #pragma unroll
    for (int c = 0; c < 8; ++c) {
        if (c < 6) {
            STAGE((c + 2) % 3, c + 2);
            asm volatile("s_waitcnt vmcnt(8)" ::: "memory");  // chunk c done, 8 in flight
        } else if (c == 6) {
            asm volatile("s_waitcnt vmcnt(4)" ::: "memory");
        } else {
            asm volatile("s_waitcnt vmcnt(0)" ::: "memory");
        }
        __builtin_amdgcn_sched_barrier(0);
        __builtin_amdgcn_s_barrier();

        const char* bufc = smem + (c % 3) * 16384;
        bf16x8 ah[4];
        #pragma unroll
        for (int i = 0; i < 4; ++i)
            ah[i] = *(const bf16x8*)(bufc + aoff + i * 1024);
        __builtin_amdgcn_s_setprio(1);
        #pragma unroll
        for (int j = 0; j < 4; ++j) {
            const bf16x8 bh = *(const bf16x8*)(bufc + 8192 + boff + j * 1024);
            #pragma unroll
            for (int i = 0; i < 4; ++i)
                acc[i][j] = __builtin_amdgcn_mfma_f32_16x16x32_bf16(ah[i], bh, acc[i][j], 0, 0, 0);
        }
        __builtin_amdgcn_s_setprio(0);
        __builtin_amdgcn_s_barrier();
    }
    #undef STAGE

    // ---- epilogue: per-wave exact local top-3, cross-wc merge, slot write ----
    float w2v[4];
    #pragma unroll
    for (int j = 0; j < 4; ++j) w2v[j] = w2[m0w + j * 16 + rl];

    __syncthreads();                    // drain LDS reads; reuse smem as exchange
    u64* ex = (u64*)smem;               // [128 rows][2 wc][3]

    #pragma unroll
    for (int i = 0; i < 4; ++i) {
        #pragma unroll
        for (int q = 0; q < 4; ++q) {
            u64 t1 = ~0ull, t2 = ~0ull, t3 = ~0ull;
            #pragma unroll
            for (int j = 0; j < 4; ++j) {
                const float d = w2v[j] - 2.0f * acc[i][j][q];
                const u64 p = packMin(d, (unsigned)(m0w + j * 16 + rl));
                if (p < t1)      { t3 = t2; t2 = t1; t1 = p; }
                else if (p < t2) { t3 = t2; t2 = p; }
                else if (p < t3) { t3 = p; }
            }
            #pragma unroll
            for (int off = 1; off <= 8; off <<= 1) {   // 16-lane group (xor<16)
                const u64 o1 = __shfl_xor(t1, off);
                const u64 o2 = __shfl_xor(t2, off);
                const u64 o3 = __shfl_xor(t3, off);
                merge3(t1, t2, t3, o1, o2, o3);
            }
            if (rl == 0) {
                const int rloc = wr * 64 + i * 16 + g * 4 + q;
                u64* e = ex + (rloc * 2 + wc) * 3;
                e[0] = t1; e[1] = t2; e[2] = t3;
            }
        }
    }
    __syncthreads();
    if (tid < 128) {                    // merge wc halves, write global slots
        const u64* e0 = ex + (tid * 2 + 0) * 3;
        const u64* e1 = ex + (tid * 2 + 1) * 3;
        u64 a1 = e0[0], a2 = e0[1], a3 = e0[2];
        merge3(a1, a2, a3, e1[0], e1[1], e1[2]);
        const size_t row = b0 + tid;
        slots[row * 96 +      mt] = a1;   // plane layout [row][3][32]
        slots[row * 96 + 32 + mt] = a2;
        slots[row * 96 + 64 + mt] = a3;
    }
}

// ---------------- merge slots -> exact top-3 recheck -> locs + scatter ------
__global__ void k_merge(const u64* __restrict__ slots, const float* __restrict__ X,
                        const float* __restrict__ W, const float* __restrict__ w2,
                        float* __restrict__ out_locs, float* __restrict__ A,
                        float* __restrict__ cnt) {
    const int wid = threadIdx.x >> 6, l = threadIdx.x & 63;
    const int row = blockIdx.x * 4 + wid;
    u64 t1, t2, t3;
    if (l < 32) {
        const u64* s = slots + (size_t)row * 96;
        t1 = s[l]; t2 = s[32 + l]; t3 = s[64 + l];
    } else { t1 = t2 = t3 = ~0ull; }
    #pragma unroll
    for (int off = 1; off <= 32; off <<= 1) {
        const u64 o1 = __shfl_xor(t1, off);
        const u64 o2 = __shfl_xor(t2, off);
        const u64 o3 = __shfl_xor(t3, off);
        merge3(t1, t2, t3, o1, o2, o3);
    }
    const int cand[3] = {(int)(t1 & 0xFFFFFFFFull), (int)(t2 & 0xFFFFFFFFull),
                         (int)(t3 & 0xFFFFFFFFull)};
    const float4 xv = *(const float4*)(X + (size_t)row * DIM + l * 4);
    float bd = 0.0f; int bm = -1;
    #pragma unroll
    for (int tix = 0; tix < 3; ++tix) {
        const int mc = cand[tix];
        const float4 wv = *(const float4*)(W + (size_t)mc * DIM + l * 4);
        float s = xv.x * wv.x + xv.y * wv.y + xv.z * wv.z + xv.w * wv.w;
        #pragma unroll
        for (int off = 1; off <= 32; off <<= 1) s += __shfl_xor(s, off);
        const float d = w2[mc] - 2.0f * s;
        if (bm < 0 || d < bd || (d == bd && mc < bm)) { bd = d; bm = mc; }
    }
    if (l == 0) {
        out_locs[row * 2 + 0] = (float)(bm >> 6);
        out_locs[row * 2 + 1] = (float)(bm & 63);
        atomicAdd(&cnt[bm], 1.0f);
    }
    float* ap = A + (size_t)bm * DIM + l * 4;
    atomicAdd(ap + 0, xv.x);
    atomicAdd(ap + 1, xv.y);
    atomicAdd(ap + 2, xv.z);
    atomicAdd(ap + 3, xv.w);
}

// ---------------- conv pass 1 (over gj) + cnt1 on extra blocks ----------------
__global__ void k_conv1(const float* __restrict__ A, const float* __restrict__ E,
                        float* __restrict__ T1, const float* __restrict__ cnt,
                        float* __restrict__ c1) {
    if (blockIdx.x >= 4096) {   // cnt1
        int t = (blockIdx.x - 4096) * 256 + threadIdx.x;
        int gi = t >> 6, mj = t & 63;
        float acc = 0.0f;
        #pragma unroll
        for (int gj = 0; gj < 64; ++gj) {
            int dd = mj - gj; dd = dd < 0 ? -dd : dd;
            acc += E[dd] * cnt[gi * 64 + gj];
        }
        c1[gi * 64 + mj] = acc;
        return;
    }
    __shared__ float Es[64];
    const int d = threadIdx.x;
    if (d < 64) Es[d] = E[d];
    __syncthreads();
    const int gi = blockIdx.x >> 6, mj = blockIdx.x & 63;
    const float* base = A + (size_t)gi * 64 * DIM + d;
    float acc = 0.0f;
    #pragma unroll
    for (int gj = 0; gj < 64; ++gj) {
        int dd = mj - gj; dd = dd < 0 ? -dd : dd;
        acc += Es[dd] * base[(size_t)gj * DIM];
    }
    T1[(size_t)blockIdx.x * DIM + d] = acc;   // [gi][mj][d]
}

// ---------------- conv pass 2 (over gi) + inline den + divide + write --------
__global__ void k_conv2(const float* __restrict__ T1, const float* __restrict__ scal,
                        const float* __restrict__ c1, float* __restrict__ outw) {
    __shared__ float Es[64];
    __shared__ float salpha;
    const int d = threadIdx.x;
    if (d < 64) Es[d] = scal[d];
    if (d == 64) salpha = scal[64];
    __syncthreads();
    const int mi = blockIdx.x >> 6, mj = blockIdx.x & 63;
    float acc = 0.0f, den = 0.0f;
    #pragma unroll
    for (int gi = 0; gi < 64; ++gi) {
        int dd = mi - gi; dd = dd < 0 ? -dd : dd;
        acc += Es[dd] * T1[((size_t)gi * 64 + mj) * DIM + d];
        den += Es[dd] * c1[gi * 64 + mj];
    }
    const float a = salpha;
    const float v = (a * acc) / (a * den + 1e-12f);
    outw[((size_t)mi * 64 + mj) * DIM + d] = v;
}

// ---------------- launcher ----------------
extern "C" void kernel_launch(void* const* d_in, const int* in_sizes, int n_in,
                              void* d_out, int out_size, void* d_ws, size_t ws_size,
                              hipStream_t stream) {
    const float* X = (const float*)d_in[0];
    const float* W = (const float*)d_in[1];
    const int*   ep = (const int*)d_in[2];
    float* out = (float*)d_out;

    char* ws = (char*)d_ws;
    u64*   slots = (u64*)(ws + 0);                 // 6 MB  [8192][3][32]
    u16*   Xh   = (u16*)(ws + 6291456);            // 4 MB
    float* A    = (float*)(ws + 6291456);          // 4 MB (aliases Xh, dead after gemm)
    float* cnt  = (float*)(ws + 10485760);         // 16 KB
    u16*   Wh   = (u16*)(ws + 10502144);           // 2 MB
    float* w2   = (float*)(ws + 12599296);         // 16 KB
    float* scal = (float*)(ws + 12615680);         // 65 floats
    float* c1   = (float*)(ws + 12616192);         // 16 KB
    float* T1   = (float*)(ws + 0);                // 4 MB (aliases slots, dead after merge)

    k_prep<<<3073, 256, 0, stream>>>(X, W, Xh, Wh, w2, ep, scal);
    k_gemm_argmin<<<2048, 256, 0, stream>>>(Xh, Wh, w2, slots);
    hipMemsetAsync(ws + 6291456, 0, 4194304 + 16384, stream);   // A + cnt = 0 (post-gemm)
    k_merge<<<2048, 256, 0, stream>>>(slots, X, W, w2, out, A, cnt);
    k_conv1<<<4112, 256, 0, stream>>>(A, scal, T1, cnt, c1);
    k_conv2<<<4096, 256, 0, stream>>>(T1, scal, c1, out + 16384);
}

// Round 6
// 172.811 us; speedup vs baseline: 1.6016x; 1.1603x over previous
//
#include <hip/hip_runtime.h>
#include <stdint.h>

#define DIM   256
#define BATCH 8192
#define MCELL 4096

typedef unsigned long long u64;
typedef unsigned short u16;
typedef __attribute__((ext_vector_type(8))) short bf16x8;   // 8 bf16 = 4 VGPRs
typedef __attribute__((ext_vector_type(4))) float f32x4;

// ---------------- helpers ----------------
__device__ __forceinline__ u64 packMin(float v, unsigned idx) {
    unsigned u = __float_as_uint(v);
    u = (u & 0x80000000u) ? ~u : (u | 0x80000000u);   // order-preserving f32->u32
    return ((u64)u << 32) | (u64)idx;
}
__device__ __forceinline__ u16 f2bf(float f) {        // RN-even f32->bf16 (bits)
    unsigned u = __float_as_uint(f);
    u += 0x7fffu + ((u >> 16) & 1u);
    return (u16)(u >> 16);
}
__device__ __forceinline__ void gll16(const void* g, const char* l) {
    __builtin_amdgcn_global_load_lds(
        (const __attribute__((address_space(1))) unsigned int*)g,
        (__attribute__((address_space(3))) unsigned int*)l, 16, 0, 0);
}
__device__ __forceinline__ u64 umin64(u64 a, u64 b) { return a < b ? a : b; }
__device__ __forceinline__ u64 umax64(u64 a, u64 b) { return a < b ? b : a; }
// sorted-pair insert
__device__ __forceinline__ void ins2(u64& t1, u64& t2, u64 p) {
    u64 hi = umax64(p, t1);
    t1 = umin64(p, t1);
    t2 = umin64(t2, hi);
}
// merge two sorted pairs -> sorted top-2 of union
__device__ __forceinline__ void merge2(u64& a1, u64& a2, u64 o1, u64 o2) {
    u64 H1 = umax64(a1, o1);
    a1 = umin64(a1, o1);
    a2 = umin64(H1, umin64(a2, o2));
}
// merge two sorted triples -> sorted top-3 of union
__device__ __forceinline__ void merge3(u64& a1, u64& a2, u64& a3,
                                       u64 o1, u64 o2, u64 o3) {
    u64 L1 = umin64(a1, o1), H1 = umax64(a1, o1);
    u64 L2 = umin64(a2, o2);
    u64 L3 = umin64(a3, o3);
    a1 = L1;
    a2 = umin64(H1, L2);
    a3 = umin64(umax64(H1, L2), L3);
}

// ---------------- prep: bf16 casts + w2 + scal, one launch ----------------
__global__ void k_prep(const float* __restrict__ X, const float* __restrict__ W,
                       u16* __restrict__ Xh, u16* __restrict__ Wh,
                       float* __restrict__ w2, const int* __restrict__ epoch_p,
                       float* __restrict__ scal) {
    const int blk = blockIdx.x;
    const int t = threadIdx.x;
    if (blk == 3072) {   // scal: E[64] table + alpha
        int raw = epoch_p[0];
        float ep = (raw >= 0 && raw < 100000) ? (float)raw : __int_as_float(raw);
        float radius = 32.0f - ep * (31.0f / 99.0f);
        float alpha  = 0.1f * (1.0f - ep / 100.0f);
        float rs = radius * 0.5f;
        float denom = 2.0f * rs * rs;
        if (t < 64)       scal[t]  = expf(-((float)(t * t)) / denom);
        else if (t == 64) scal[64] = alpha;
        return;
    }
    if (blk < 2048) {            // X cast
        const int fi = blk * 256 + t;
        float4 v = ((const float4*)X)[fi];
        ushort4 h = {f2bf(v.x), f2bf(v.y), f2bf(v.z), f2bf(v.w)};
        ((ushort4*)Xh)[fi] = h;
    } else {                     // W cast + w2
        const int fi = (blk - 2048) * 256 + t;
        float4 v = ((const float4*)W)[fi];
        ushort4 h = {f2bf(v.x), f2bf(v.y), f2bf(v.z), f2bf(v.w)};
        ((ushort4*)Wh)[fi] = h;
        float s = v.x * v.x + v.y * v.y + v.z * v.z + v.w * v.w;
        #pragma unroll
        for (int off = 32; off; off >>= 1) s += __shfl_down(s, off);
        if ((t & 63) == 0) w2[fi >> 6] = s;
    }
}

// ---------------- hi-only bf16 MFMA GEMM, SWAPPED operands ------------------
// block 128b x 128m, 4 waves (wr: m-half, wc: b-half), wave 64m x 64b.
// acc rows = m (thread-local!), cols = b. Top-2 per (b-row, wave-64m) with
// in-register inserts + 2 shuffle rounds; deterministic slot writes.
__global__ __launch_bounds__(256, 3)
void k_gemm_argmin(const u16* __restrict__ Xh, const u16* __restrict__ Wh,
                   const float* __restrict__ w2, u64* __restrict__ slots) {
    __shared__ char smem[49152];
    const int wg = blockIdx.x;
    const int swz = (wg & 7) * 256 + (wg >> 3);   // XCD-chunked, bijective (2048%8==0)
    const int bt = swz >> 5;                      // 0..63
    const int mt = swz & 31;                      // 0..31
    const int tid = threadIdx.x;
    const int wid = tid >> 6;
    const int lane = tid & 63;
    const int wr = wid >> 1, wc = wid & 1;        // wr: m-half, wc: b-half
    const int b0 = bt * 128, m0 = mt * 128;

    // staging addrs (per wave 2 issues per array; rows [wid*32,+16), [+16,+16))
    const int sr0 = wid * 32 + (lane >> 2);
    const int sr1 = sr0 + 16;
    const int ss  = lane & 3;
    const int sg0 = ss ^ ((sr0 >> 1) & 3);        // pre-swizzled global slot
    const int sg1 = ss ^ ((sr1 >> 1) & 3);
    const size_t gA0 = (size_t)(b0 + sr0) * DIM + sg0 * 8;   // X rows
    const size_t gA1 = (size_t)(b0 + sr1) * DIM + sg1 * 8;
    const size_t gB0 = (size_t)(m0 + sr0) * DIM + sg0 * 8;   // W rows
    const size_t gB1 = (size_t)(m0 + sr1) * DIM + sg1 * 8;
    const int ldsA = wid * 2048;                  // wave-uniform within 8KB region

    // fragment read offsets (swizzled, both-sides involution)
    const int rl = lane & 15, g = lane >> 4;
    const int slot = g ^ ((rl >> 1) & 3);
    const int xoff = (wc * 64 + rl) * 64 + slot * 16;   // + j*1024 (Xh region @0)
    const int woff = (wr * 64 + rl) * 64 + slot * 16;   // + i*1024 (Wh region @8192)

    f32x4 acc[4][4];
    #pragma unroll
    for (int i = 0; i < 4; ++i)
        #pragma unroll
        for (int j = 0; j < 4; ++j) acc[i][j] = (f32x4){0.f, 0.f, 0.f, 0.f};

    #define STAGE(buf, c) do {                                                \
        char* base_ = smem + (buf) * 16384;                                   \
        const int co_ = (c) * 32;                                             \
        gll16(Xh + gA0 + co_, base_ + ldsA);                                  \
        gll16(Xh + gA1 + co_, base_ + ldsA + 1024);                           \
        gll16(Wh + gB0 + co_, base_ + 8192 + ldsA);                           \
        gll16(Wh + gB1 + co_, base_ + 8192 + ldsA + 1024);                    \
    } while (0)

    STAGE(0, 0);
    STAGE(1, 1);
    #pragma unroll
    for (int c = 0; c < 8; ++c) {
        if (c < 6) {
            STAGE((c + 2) % 3, c + 2);
            asm volatile("s_waitcnt vmcnt(8)" ::: "memory");  // chunk c done, 8 in flight
        } else if (c == 6) {
            asm volatile("s_waitcnt vmcnt(4)" ::: "memory");
        } else {
            asm volatile("s_waitcnt vmcnt(0)" ::: "memory");
        }
        __builtin_amdgcn_sched_barrier(0);
        __builtin_amdgcn_s_barrier();

        const char* bufc = smem + (c % 3) * 16384;
        bf16x8 wf[4];
        #pragma unroll
        for (int i = 0; i < 4; ++i)
            wf[i] = *(const bf16x8*)(bufc + 8192 + woff + i * 1024);
        __builtin_amdgcn_s_setprio(1);
        #pragma unroll
        for (int j = 0; j < 4; ++j) {
            const bf16x8 xf = *(const bf16x8*)(bufc + xoff + j * 1024);
            #pragma unroll
            for (int i = 0; i < 4; ++i)   // D rows = m, D cols = b
                acc[i][j] = __builtin_amdgcn_mfma_f32_16x16x32_bf16(wf[i], xf, acc[i][j], 0, 0, 0);
        }
        __builtin_amdgcn_s_setprio(0);
        __builtin_amdgcn_s_barrier();
    }
    #undef STAGE

    // ---- epilogue: m is thread-local -> register top-2, 2 shuffle rounds ----
    float w2v[16];
    #pragma unroll
    for (int ii = 0; ii < 16; ++ii)
        w2v[ii] = w2[m0 + wr * 64 + (ii >> 2) * 16 + g * 4 + (ii & 3)];

    __syncthreads();                    // all LDS reads retired; reuse smem
    u64* ex = (u64*)smem;               // [128 b-local][2 wr][2]

    #pragma unroll
    for (int j = 0; j < 4; ++j) {       // b-col = wc*64 + j*16 + rl
        u64 t1 = ~0ull, t2 = ~0ull;
        #pragma unroll
        for (int i = 0; i < 4; ++i)
            #pragma unroll
            for (int q = 0; q < 4; ++q) {
                const float d = fmaf(-2.0f, acc[i][j][q], w2v[i * 4 + q]);
                ins2(t1, t2, packMin(d, (unsigned)(m0 + wr * 64 + i * 16 + g * 4 + q)));
            }
        #pragma unroll
        for (int off = 16; off <= 32; off <<= 1) {   // merge across g
            const u64 o1 = __shfl_xor(t1, off);
            const u64 o2 = __shfl_xor(t2, off);
            merge2(t1, t2, o1, o2);
        }
        if (lane < 16) {                // g==0 lanes write
            u64* e = ex + ((size_t)(wc * 64 + j * 16 + rl) * 2 + wr) * 2;
            e[0] = t1; e[1] = t2;
        }
    }
    __syncthreads();
    if (tid < 128) {                    // merge wr halves, write global slots
        const u64* e = ex + (size_t)tid * 4;
        u64 a1 = e[0], a2 = e[1];
        merge2(a1, a2, e[2], e[3]);
        slots[(size_t)(b0 + tid) * 64 + mt]      = a1;   // [row][2 ranks][32 mt]
        slots[(size_t)(b0 + tid) * 64 + 32 + mt] = a2;
    }
}

// ---------------- merge slots -> exact top-3 recheck -> locs + scatter ------
__global__ void k_merge(const u64* __restrict__ slots, const float* __restrict__ X,
                        const float* __restrict__ W, const float* __restrict__ w2,
                        float* __restrict__ out_locs, float* __restrict__ A,
                        float* __restrict__ cnt) {
    const int wid = threadIdx.x >> 6, l = threadIdx.x & 63;
    const int row = blockIdx.x * 4 + wid;
    u64 t1 = slots[(size_t)row * 64 + l], t2 = ~0ull, t3 = ~0ull;
    #pragma unroll
    for (int off = 1; off <= 32; off <<= 1) {
        const u64 o1 = __shfl_xor(t1, off);
        const u64 o2 = __shfl_xor(t2, off);
        const u64 o3 = __shfl_xor(t3, off);
        merge3(t1, t2, t3, o1, o2, o3);
    }
    const int cand[3] = {(int)(t1 & 0xFFFFFFFFull), (int)(t2 & 0xFFFFFFFFull),
                         (int)(t3 & 0xFFFFFFFFull)};
    const float4 xv = *(const float4*)(X + (size_t)row * DIM + l * 4);
    float bd = 0.0f; int bm = -1;
    #pragma unroll
    for (int tix = 0; tix < 3; ++tix) {
        const int mc = cand[tix];
        const float4 wv = *(const float4*)(W + (size_t)mc * DIM + l * 4);
        float s = xv.x * wv.x + xv.y * wv.y + xv.z * wv.z + xv.w * wv.w;
        #pragma unroll
        for (int off = 1; off <= 32; off <<= 1) s += __shfl_xor(s, off);
        const float d = w2[mc] - 2.0f * s;
        if (bm < 0 || d < bd || (d == bd && mc < bm)) { bd = d; bm = mc; }
    }
    if (l == 0) {
        out_locs[row * 2 + 0] = (float)(bm >> 6);
        out_locs[row * 2 + 1] = (float)(bm & 63);
        atomicAdd(&cnt[bm], 1.0f);
    }
    float* ap = A + (size_t)bm * DIM + l * 4;
    atomicAdd(ap + 0, xv.x);
    atomicAdd(ap + 1, xv.y);
    atomicAdd(ap + 2, xv.z);
    atomicAdd(ap + 3, xv.w);
}

// ---------------- conv pass 1 (over gj) + cnt1 on extra blocks ----------------
__global__ void k_conv1(const float* __restrict__ A, const float* __restrict__ E,
                        float* __restrict__ T1, const float* __restrict__ cnt,
                        float* __restrict__ c1) {
    if (blockIdx.x >= 4096) {   // cnt1
        int t = (blockIdx.x - 4096) * 256 + threadIdx.x;
        int gi = t >> 6, mj = t & 63;
        float acc = 0.0f;
        #pragma unroll
        for (int gj = 0; gj < 64; ++gj) {
            int dd = mj - gj; dd = dd < 0 ? -dd : dd;
            acc += E[dd] * cnt[gi * 64 + gj];
        }
        c1[gi * 64 + mj] = acc;
        return;
    }
    __shared__ float Es[64];
    const int d = threadIdx.x;
    if (d < 64) Es[d] = E[d];
    __syncthreads();
    const int gi = blockIdx.x >> 6, mj = blockIdx.x & 63;
    const float* base = A + (size_t)gi * 64 * DIM + d;
    float acc = 0.0f;
    #pragma unroll
    for (int gj = 0; gj < 64; ++gj) {
        int dd = mj - gj; dd = dd < 0 ? -dd : dd;
        acc += Es[dd] * base[(size_t)gj * DIM];
    }
    T1[(size_t)blockIdx.x * DIM + d] = acc;   // [gi][mj][d]
}

// ---------------- conv pass 2 (over gi) + inline den + divide + write --------
__global__ void k_conv2(const float* __restrict__ T1, const float* __restrict__ scal,
                        const float* __restrict__ c1, float* __restrict__ outw) {
    __shared__ float Es[64];
    __shared__ float salpha;
    const int d = threadIdx.x;
    if (d < 64) Es[d] = scal[d];
    if (d == 64) salpha = scal[64];
    __syncthreads();
    const int mi = blockIdx.x >> 6, mj = blockIdx.x & 63;
    float acc = 0.0f, den = 0.0f;
    #pragma unroll
    for (int gi = 0; gi < 64; ++gi) {
        int dd = mi - gi; dd = dd < 0 ? -dd : dd;
        acc += Es[dd] * T1[((size_t)gi * 64 + mj) * DIM + d];
        den += Es[dd] * c1[gi * 64 + mj];
    }
    const float a = salpha;
    const float v = (a * acc) / (a * den + 1e-12f);
    outw[((size_t)mi * 64 + mj) * DIM + d] = v;
}

// ---------------- launcher ----------------
extern "C" void kernel_launch(void* const* d_in, const int* in_sizes, int n_in,
                              void* d_out, int out_size, void* d_ws, size_t ws_size,
                              hipStream_t stream) {
    const float* X = (const float*)d_in[0];
    const float* W = (const float*)d_in[1];
    const int*   ep = (const int*)d_in[2];
    float* out = (float*)d_out;

    char* ws = (char*)d_ws;
    u64*   slots = (u64*)(ws + 0);                     // 4 MB [8192][64]
    float* T1    = (float*)(ws + 0);                   // alias (after merge)
    u16*   Xh    = (u16*)(ws + (4u << 20));            // 4 MB
    float* A     = (float*)(ws + (4u << 20));          // alias (after gemm)
    float* cnt   = (float*)(ws + (8u << 20));          // 16 KB (adjacent to A)
    u16*   Wh    = (u16*)(ws + (8u << 20) + 16384);    // 2 MB
    float* w2    = (float*)(ws + (10u << 20) + 16384); // 16 KB
    float* scal  = (float*)(ws + (10u << 20) + 32768); // 65 floats
    float* c1    = (float*)(ws + (10u << 20) + 36864); // 16 KB

    k_prep<<<3073, 256, 0, stream>>>(X, W, Xh, Wh, w2, ep, scal);
    k_gemm_argmin<<<2048, 256, 0, stream>>>(Xh, Wh, w2, slots);
    hipMemsetAsync(ws + (4u << 20), 0, (4u << 20) + 16384, stream);  // A + cnt = 0
    k_merge<<<2048, 256, 0, stream>>>(slots, X, W, w2, out, A, cnt);
    k_conv1<<<4112, 256, 0, stream>>>(A, scal, T1, cnt, c1);
    k_conv2<<<4096, 256, 0, stream>>>(T1, scal, c1, out + 16384);
}

// Round 7
// 163.102 us; speedup vs baseline: 1.6969x; 1.0595x over previous
//
#include <hip/hip_runtime.h>
#include <stdint.h>

#define DIM   256
#define BATCH 8192
#define MCELL 4096

typedef unsigned long long u64;
typedef unsigned short u16;
typedef __attribute__((ext_vector_type(8))) short bf16x8;   // 8 bf16 = 4 VGPRs
typedef __attribute__((ext_vector_type(4))) float f32x4;

// ---------------- helpers ----------------
__device__ __forceinline__ u64 packMin(float v, unsigned idx) {
    unsigned u = __float_as_uint(v);
    u = (u & 0x80000000u) ? ~u : (u | 0x80000000u);   // order-preserving f32->u32
    return ((u64)u << 32) | (u64)idx;
}
__device__ __forceinline__ u16 f2bf(float f) {        // RN-even f32->bf16 (bits)
    unsigned u = __float_as_uint(f);
    u += 0x7fffu + ((u >> 16) & 1u);
    return (u16)(u >> 16);
}
__device__ __forceinline__ void gll16(const void* g, const char* l) {
    __builtin_amdgcn_global_load_lds(
        (const __attribute__((address_space(1))) unsigned int*)g,
        (__attribute__((address_space(3))) unsigned int*)l, 16, 0, 0);
}
__device__ __forceinline__ u64 umin64(u64 a, u64 b) { return a < b ? a : b; }
__device__ __forceinline__ u64 umax64(u64 a, u64 b) { return a < b ? b : a; }
// sorted-pair insert
__device__ __forceinline__ void ins2(u64& t1, u64& t2, u64 p) {
    u64 hi = umax64(p, t1);
    t1 = umin64(p, t1);
    t2 = umin64(t2, hi);
}
// merge two sorted pairs -> sorted top-2 of union
__device__ __forceinline__ void merge2(u64& a1, u64& a2, u64 o1, u64 o2) {
    u64 H1 = umax64(a1, o1);
    a1 = umin64(a1, o1);
    a2 = umin64(H1, umin64(a2, o2));
}
// merge two sorted triples -> sorted top-3 of union
__device__ __forceinline__ void merge3(u64& a1, u64& a2, u64& a3,
                                       u64 o1, u64 o2, u64 o3) {
    u64 L1 = umin64(a1, o1), H1 = umax64(a1, o1);
    u64 L2 = umin64(a2, o2);
    u64 L3 = umin64(a3, o3);
    a1 = L1;
    a2 = umin64(H1, L2);
    a3 = umin64(umax64(H1, L2), L3);
}

// ---------------- prep: bf16 casts + w2 + scal, one launch ----------------
__global__ void k_prep(const float* __restrict__ X, const float* __restrict__ W,
                       u16* __restrict__ Xh, u16* __restrict__ Wh,
                       float* __restrict__ w2, const int* __restrict__ epoch_p,
                       float* __restrict__ scal) {
    const int blk = blockIdx.x;
    const int t = threadIdx.x;
    if (blk == 3072) {   // scal: E[64] table + alpha
        int raw = epoch_p[0];
        float ep = (raw >= 0 && raw < 100000) ? (float)raw : __int_as_float(raw);
        float radius = 32.0f - ep * (31.0f / 99.0f);
        float alpha  = 0.1f * (1.0f - ep / 100.0f);
        float rs = radius * 0.5f;
        float denom = 2.0f * rs * rs;
        if (t < 64)       scal[t]  = expf(-((float)(t * t)) / denom);
        else if (t == 64) scal[64] = alpha;
        return;
    }
    if (blk < 2048) {            // X cast
        const int fi = blk * 256 + t;
        float4 v = ((const float4*)X)[fi];
        ushort4 h = {f2bf(v.x), f2bf(v.y), f2bf(v.z), f2bf(v.w)};
        ((ushort4*)Xh)[fi] = h;
    } else {                     // W cast + w2
        const int fi = (blk - 2048) * 256 + t;
        float4 v = ((const float4*)W)[fi];
        ushort4 h = {f2bf(v.x), f2bf(v.y), f2bf(v.z), f2bf(v.w)};
        ((ushort4*)Wh)[fi] = h;
        float s = v.x * v.x + v.y * v.y + v.z * v.z + v.w * v.w;
        #pragma unroll
        for (int off = 32; off; off >>= 1) s += __shfl_down(s, off);
        if ((t & 63) == 0) w2[fi >> 6] = s;
    }
}

// ---------------- hi-only bf16 MFMA GEMM, SWAPPED operands ------------------
// block 128b x 128m, 4 waves (wr: m-half, wc: b-half), wave 64m x 64b.
// acc rows = m (thread-local!), cols = b. Top-2 per (b-row, wave-64m) with
// in-register inserts + 2 shuffle rounds; deterministic slot writes.
__global__ __launch_bounds__(256, 3)
void k_gemm_argmin(const u16* __restrict__ Xh, const u16* __restrict__ Wh,
                   const float* __restrict__ w2, u64* __restrict__ slots) {
    __shared__ char smem[49152];
    const int wg = blockIdx.x;
    const int swz = (wg & 7) * 256 + (wg >> 3);   // XCD-chunked, bijective (2048%8==0)
    const int bt = swz >> 5;                      // 0..63
    const int mt = swz & 31;                      // 0..31
    const int tid = threadIdx.x;
    const int wid = tid >> 6;
    const int lane = tid & 63;
    const int wr = wid >> 1, wc = wid & 1;        // wr: m-half, wc: b-half
    const int b0 = bt * 128, m0 = mt * 128;

    // staging addrs (per wave 2 issues per array; rows [wid*32,+16), [+16,+16))
    const int sr0 = wid * 32 + (lane >> 2);
    const int sr1 = sr0 + 16;
    const int ss  = lane & 3;
    const int sg0 = ss ^ ((sr0 >> 1) & 3);        // pre-swizzled global slot
    const int sg1 = ss ^ ((sr1 >> 1) & 3);
    const size_t gA0 = (size_t)(b0 + sr0) * DIM + sg0 * 8;   // X rows
    const size_t gA1 = (size_t)(b0 + sr1) * DIM + sg1 * 8;
    const size_t gB0 = (size_t)(m0 + sr0) * DIM + sg0 * 8;   // W rows
    const size_t gB1 = (size_t)(m0 + sr1) * DIM + sg1 * 8;
    const int ldsA = wid * 2048;                  // wave-uniform within 8KB region

    // fragment read offsets (swizzled, both-sides involution)
    const int rl = lane & 15, g = lane >> 4;
    const int slot = g ^ ((rl >> 1) & 3);
    const int xoff = (wc * 64 + rl) * 64 + slot * 16;   // + j*1024 (Xh region @0)
    const int woff = (wr * 64 + rl) * 64 + slot * 16;   // + i*1024 (Wh region @8192)

    f32x4 acc[4][4];
    #pragma unroll
    for (int i = 0; i < 4; ++i)
        #pragma unroll
        for (int j = 0; j < 4; ++j) acc[i][j] = (f32x4){0.f, 0.f, 0.f, 0.f};

    #define STAGE(buf, c) do {                                                \
        char* base_ = smem + (buf) * 16384;                                   \
        const int co_ = (c) * 32;                                             \
        gll16(Xh + gA0 + co_, base_ + ldsA);                                  \
        gll16(Xh + gA1 + co_, base_ + ldsA + 1024);                           \
        gll16(Wh + gB0 + co_, base_ + 8192 + ldsA);                           \
        gll16(Wh + gB1 + co_, base_ + 8192 + ldsA + 1024);                    \
    } while (0)

    STAGE(0, 0);
    STAGE(1, 1);
    #pragma unroll
    for (int c = 0; c < 8; ++c) {
        if (c < 6) {
            STAGE((c + 2) % 3, c + 2);
            asm volatile("s_waitcnt vmcnt(8)" ::: "memory");  // chunk c done, 8 in flight
        } else if (c == 6) {
            asm volatile("s_waitcnt vmcnt(4)" ::: "memory");
        } else {
            asm volatile("s_waitcnt vmcnt(0)" ::: "memory");
        }
        __builtin_amdgcn_sched_barrier(0);
        __builtin_amdgcn_s_barrier();

        const char* bufc = smem + (c % 3) * 16384;
        bf16x8 wf[4];
        #pragma unroll
        for (int i = 0; i < 4; ++i)
            wf[i] = *(const bf16x8*)(bufc + 8192 + woff + i * 1024);
        __builtin_amdgcn_s_setprio(1);
        #pragma unroll
        for (int j = 0; j < 4; ++j) {
            const bf16x8 xf = *(const bf16x8*)(bufc + xoff + j * 1024);
            #pragma unroll
            for (int i = 0; i < 4; ++i)   // D rows = m, D cols = b
                acc[i][j] = __builtin_amdgcn_mfma_f32_16x16x32_bf16(wf[i], xf, acc[i][j], 0, 0, 0);
        }
        __builtin_amdgcn_s_setprio(0);
        __builtin_amdgcn_s_barrier();
    }
    #undef STAGE

    // ---- epilogue: m is thread-local -> register top-2, 2 shuffle rounds ----
    float w2v[16];
    #pragma unroll
    for (int ii = 0; ii < 16; ++ii)
        w2v[ii] = w2[m0 + wr * 64 + (ii >> 2) * 16 + g * 4 + (ii & 3)];

    __syncthreads();                    // all LDS reads retired; reuse smem
    u64* ex = (u64*)smem;               // [128 b-local][2 wr][2]

    #pragma unroll
    for (int j = 0; j < 4; ++j) {       // b-col = wc*64 + j*16 + rl
        u64 t1 = ~0ull, t2 = ~0ull;
        #pragma unroll
        for (int i = 0; i < 4; ++i)
            #pragma unroll
            for (int q = 0; q < 4; ++q) {
                const float d = fmaf(-2.0f, acc[i][j][q], w2v[i * 4 + q]);
                ins2(t1, t2, packMin(d, (unsigned)(m0 + wr * 64 + i * 16 + g * 4 + q)));
            }
        #pragma unroll
        for (int off = 16; off <= 32; off <<= 1) {   // merge across g
            const u64 o1 = __shfl_xor(t1, off);
            const u64 o2 = __shfl_xor(t2, off);
            merge2(t1, t2, o1, o2);
        }
        if (lane < 16) {                // g==0 lanes write
            u64* e = ex + ((size_t)(wc * 64 + j * 16 + rl) * 2 + wr) * 2;
            e[0] = t1; e[1] = t2;
        }
    }
    __syncthreads();
    if (tid < 128) {                    // merge wr halves, write global slots
        const u64* e = ex + (size_t)tid * 4;
        u64 a1 = e[0], a2 = e[1];
        merge2(a1, a2, e[2], e[3]);
        slots[(size_t)(b0 + tid) * 64 + mt]      = a1;   // [row][2 ranks][32 mt]
        slots[(size_t)(b0 + tid) * 64 + 32 + mt] = a2;
    }
}

// ---------------- merge slots -> exact top-3 recheck -> locs + bmu ----------
__global__ void k_merge(const u64* __restrict__ slots, const float* __restrict__ X,
                        const float* __restrict__ W, const float* __restrict__ w2,
                        float* __restrict__ out_locs, int* __restrict__ bmu) {
    const int wid = threadIdx.x >> 6, l = threadIdx.x & 63;
    const int row = blockIdx.x * 4 + wid;
    u64 t1 = slots[(size_t)row * 64 + l], t2 = ~0ull, t3 = ~0ull;
    #pragma unroll
    for (int off = 1; off <= 32; off <<= 1) {
        const u64 o1 = __shfl_xor(t1, off);
        const u64 o2 = __shfl_xor(t2, off);
        const u64 o3 = __shfl_xor(t3, off);
        merge3(t1, t2, t3, o1, o2, o3);
    }
    const int cand[3] = {(int)(t1 & 0xFFFFFFFFull), (int)(t2 & 0xFFFFFFFFull),
                         (int)(t3 & 0xFFFFFFFFull)};
    const float4 xv = *(const float4*)(X + (size_t)row * DIM + l * 4);
    float bd = 0.0f; int bm = -1;
    #pragma unroll
    for (int tix = 0; tix < 3; ++tix) {
        const int mc = cand[tix];
        const float4 wv = *(const float4*)(W + (size_t)mc * DIM + l * 4);
        float s = xv.x * wv.x + xv.y * wv.y + xv.z * wv.z + xv.w * wv.w;
        #pragma unroll
        for (int off = 1; off <= 32; off <<= 1) s += __shfl_xor(s, off);
        const float d = w2[mc] - 2.0f * s;
        if (bm < 0 || d < bd || (d == bd && mc < bm)) { bd = d; bm = mc; }
    }
    if (l == 0) {
        out_locs[row * 2 + 0] = (float)(bm >> 6);
        out_locs[row * 2 + 1] = (float)(bm & 63);
        bmu[row] = bm;
    }
}

// ---------------- gather: per-cell sum of assigned rows (no atomics) --------
// one block per cell m; scan bmu (L2-broadcast), LDS row list, coalesced sum.
__global__ void k_gather(const int* __restrict__ bmu, const float* __restrict__ X,
                         float* __restrict__ A, float* __restrict__ cnt) {
    __shared__ int n;
    __shared__ int lst[BATCH];
    const int m = blockIdx.x;
    const int t = threadIdx.x;
    if (t == 0) n = 0;
    __syncthreads();
    #pragma unroll
    for (int i = 0; i < BATCH / 256; ++i) {
        const int r = i * 256 + t;
        if (bmu[r] == m) lst[atomicAdd(&n, 1)] = r;   // LDS atomic, rare hits
    }
    __syncthreads();
    const int nn = n;
    float acc = 0.0f;
    for (int k = 0; k < nn; ++k)
        acc += X[(size_t)lst[k] * DIM + t];
    A[(size_t)m * DIM + t] = acc;
    if (t == 0) cnt[m] = (float)nn;
}

// ---------------- conv pass 1 (over gj) + cnt1 on extra blocks ----------------
__global__ void k_conv1(const float* __restrict__ A, const float* __restrict__ E,
                        float* __restrict__ T1, const float* __restrict__ cnt,
                        float* __restrict__ c1) {
    if (blockIdx.x >= 4096) {   // cnt1
        int t = (blockIdx.x - 4096) * 256 + threadIdx.x;
        int gi = t >> 6, mj = t & 63;
        float acc = 0.0f;
        #pragma unroll
        for (int gj = 0; gj < 64; ++gj) {
            int dd = mj - gj; dd = dd < 0 ? -dd : dd;
            acc += E[dd] * cnt[gi * 64 + gj];
        }
        c1[gi * 64 + mj] = acc;
        return;
    }
    __shared__ float Es[64];
    const int d = threadIdx.x;
    if (d < 64) Es[d] = E[d];
    __syncthreads();
    const int gi = blockIdx.x >> 6, mj = blockIdx.x & 63;
    const float* base = A + (size_t)gi * 64 * DIM + d;
    float acc = 0.0f;
    #pragma unroll
    for (int gj = 0; gj < 64; ++gj) {
        int dd = mj - gj; dd = dd < 0 ? -dd : dd;
        acc += Es[dd] * base[(size_t)gj * DIM];
    }
    T1[(size_t)blockIdx.x * DIM + d] = acc;   // [gi][mj][d]
}

// ---------------- conv pass 2 (over gi) + inline den + divide + write --------
__global__ void k_conv2(const float* __restrict__ T1, const float* __restrict__ scal,
                        const float* __restrict__ c1, float* __restrict__ outw) {
    __shared__ float Es[64];
    __shared__ float salpha;
    const int d = threadIdx.x;
    if (d < 64) Es[d] = scal[d];
    if (d == 64) salpha = scal[64];
    __syncthreads();
    const int mi = blockIdx.x >> 6, mj = blockIdx.x & 63;
    float acc = 0.0f, den = 0.0f;
    #pragma unroll
    for (int gi = 0; gi < 64; ++gi) {
        int dd = mi - gi; dd = dd < 0 ? -dd : dd;
        acc += Es[dd] * T1[((size_t)gi * 64 + mj) * DIM + d];
        den += Es[dd] * c1[gi * 64 + mj];
    }
    const float a = salpha;
    const float v = (a * acc) / (a * den + 1e-12f);
    outw[((size_t)mi * 64 + mj) * DIM + d] = v;
}

// ---------------- launcher ----------------
extern "C" void kernel_launch(void* const* d_in, const int* in_sizes, int n_in,
                              void* d_out, int out_size, void* d_ws, size_t ws_size,
                              hipStream_t stream) {
    const float* X = (const float*)d_in[0];
    const float* W = (const float*)d_in[1];
    const int*   ep = (const int*)d_in[2];
    float* out = (float*)d_out;

    char* ws = (char*)d_ws;
    u64*   slots = (u64*)(ws + 0);                     // 4 MB [8192][64]
    float* T1    = (float*)(ws + 0);                   // alias (slots dead after merge)
    u16*   Xh    = (u16*)(ws + (4u << 20));            // 4 MB
    float* A     = (float*)(ws + (4u << 20));          // alias (Xh dead after gemm)
    float* cnt   = (float*)(ws + (8u << 20));          // 16 KB
    u16*   Wh    = (u16*)(ws + (8u << 20) + 16384);    // 2 MB
    float* w2    = (float*)(ws + (10u << 20) + 16384); // 16 KB
    float* scal  = (float*)(ws + (10u << 20) + 32768); // 65 floats
    float* c1    = (float*)(ws + (10u << 20) + 36864); // 16 KB
    int*   bmu   = (int*)(ws + (10u << 20) + 53248);   // 32 KB

    k_prep<<<3073, 256, 0, stream>>>(X, W, Xh, Wh, w2, ep, scal);
    k_gemm_argmin<<<2048, 256, 0, stream>>>(Xh, Wh, w2, slots);
    k_merge<<<2048, 256, 0, stream>>>(slots, X, W, w2, out, bmu);
    k_gather<<<MCELL, 256, 0, stream>>>(bmu, X, A, cnt);
    k_conv1<<<4112, 256, 0, stream>>>(A, scal, T1, cnt, c1);
    k_conv2<<<4096, 256, 0, stream>>>(T1, scal, c1, out + 16384);
}